// Round 2
// baseline (85.322 us; speedup 1.0000x reference)
//
#include <hip/hip_runtime.h>
#include <hip/hip_bf16.h>

typedef __bf16 bf16x8 __attribute__((ext_vector_type(8)));
typedef __bf16 bf16x4 __attribute__((ext_vector_type(4)));
typedef float  f32x4  __attribute__((ext_vector_type(4)));
typedef unsigned int u32x4 __attribute__((ext_vector_type(4)));

// ---------------------------------------------------------------------------
// Transpose + cast fp32 -> bf16:  dst[c][r] = (bf16)src[r][c]
// grid: (C/32, R/32), block 256 (32x8)
// ---------------------------------------------------------------------------
__global__ void tcast(const float* __restrict__ src, __bf16* __restrict__ dst,
                      int R, int C) {
    __shared__ float tile[32][33];
    const int bc = blockIdx.x * 32;   // col base in src
    const int br = blockIdx.y * 32;   // row base in src
    const int tx = threadIdx.x & 31;
    const int ty = threadIdx.x >> 5;  // 0..7
#pragma unroll
    for (int p = 0; p < 4; ++p)
        tile[ty + p * 8][tx] = src[(size_t)(br + ty + p * 8) * C + bc + tx];
    __syncthreads();
#pragma unroll
    for (int p = 0; p < 4; ++p)
        dst[(size_t)(bc + ty + p * 8) * R + br + tx] = (__bf16)tile[tx][ty + p * 8];
}

// ---------------------------------------------------------------------------
// Fused: out[8192][4096](f32) = (inp[8192][4096](f32) @ A) @ B
// A given as At[128][4096] bf16, B given as Bt[4096][128] bf16.
// 256 blocks (1/CU) x 512 threads (8 waves). BM=32 rows per block.
//
// Phase A: U[32][128] = inp_tile @ A.  Double-buffered LDS staging of inp
//          (fp32->bf16 reg convert) and At; 2x{16x16x32} MFMA per wave per
//          half-K-tile; wave grid 2M x 4N. Accumulate in regs.
// Phase B: U -> LDS (bf16, swizzled), one barrier, then each wave owns all
//          32 rows x a 512-col slice of out; Bt fragments read directly from
//          global (L2-resident); barrier-free streaming; fp32 stores.
// ---------------------------------------------------------------------------
__global__ __launch_bounds__(512, 1) void fused_lora(
        const float* __restrict__ inp,
        const __bf16* __restrict__ At,
        const __bf16* __restrict__ Bt,
        float* __restrict__ out) {
    __shared__ __align__(16) __bf16 sI[2][32][64];    // 2 x 4 KB
    __shared__ __align__(16) __bf16 sA[2][128][64];   // 2 x 16 KB
    __shared__ __align__(16) __bf16 sU[32][128];      // 8 KB
    const int t    = threadIdx.x;
    const int brow = blockIdx.x * 32;
    const int lane = t & 63;
    const int wid  = t >> 6;

    // fragment geometry (shared by both phases)
    const int fr = lane & 15;
    const int fk = (lane >> 4) << 3;    // 0,8,16,24

    // ---------------- Phase A ----------------
    const int wm   = (wid >> 2) << 4;   // 0 / 16
    const int wn   = (wid & 3) << 5;    // 0 / 32 / 64 / 96

    // staging geometry
    const int irow = t >> 4;            // 0..31
    const int icol = (t & 15) << 2;     // 0..60, step 4

    f32x4 acc[2] = {};
    f32x4 ireg;
    u32x4 areg[2];

    auto load_tile = [&](int kt) {
        ireg = *reinterpret_cast<const f32x4*>(
            &inp[(size_t)(brow + irow) * 4096 + kt * 64 + icol]);
#pragma unroll
        for (int p = 0; p < 2; ++p) {
            const int c = t + p * 512;
            const int row = c >> 3, col = (c & 7) << 3;
            areg[p] = *reinterpret_cast<const u32x4*>(
                &At[(size_t)row * 4096 + kt * 64 + col]);
        }
    };
    auto store_tile = [&](int buf) {
        bf16x4 h = { (__bf16)ireg[0], (__bf16)ireg[1], (__bf16)ireg[2], (__bf16)ireg[3] };
        *reinterpret_cast<bf16x4*>(&sI[buf][irow][icol ^ ((irow & 7) << 3)]) = h;
#pragma unroll
        for (int p = 0; p < 2; ++p) {
            const int c = t + p * 512;
            const int row = c >> 3, col = (c & 7) << 3;
            *reinterpret_cast<u32x4*>(&sA[buf][row][col ^ ((row & 7) << 3)]) = areg[p];
        }
    };

    load_tile(0);
    store_tile(0);
    int cur = 0;
    for (int kt = 0; kt < 64; ++kt) {
        if (kt < 63) load_tile(kt + 1);       // overlap with compute below
        __syncthreads();                      // buf[cur] writes visible
#pragma unroll
        for (int ks = 0; ks < 2; ++ks) {
            const int k = ks * 32 + fk;
            const int ar = wm + fr;
            bf16x8 af = *reinterpret_cast<const bf16x8*>(
                &sI[cur][ar][k ^ ((ar & 7) << 3)]);
#pragma unroll
            for (int n = 0; n < 2; ++n) {
                const int nr = wn + n * 16 + fr;
                bf16x8 bfv = *reinterpret_cast<const bf16x8*>(
                    &sA[cur][nr][k ^ ((nr & 7) << 3)]);
                acc[n] = __builtin_amdgcn_mfma_f32_16x16x32_bf16(af, bfv, acc[n], 0, 0, 0);
            }
        }
        __syncthreads();                      // all reads of buf[cur] done
        if (kt < 63) store_tile(cur ^ 1);
        cur ^= 1;
    }

    // U -> LDS (bf16, swizzled).  C/D layout: col=lane&15, row=(lane>>4)*4+v
    {
        const int r0 = wm + ((lane >> 4) << 2);
#pragma unroll
        for (int n = 0; n < 2; ++n) {
            const int c = wn + n * 16 + fr;
#pragma unroll
            for (int v = 0; v < 4; ++v) {
                const int r = r0 + v;
                sU[r][c ^ ((r & 7) << 3)] = (__bf16)acc[n][v];
            }
        }
    }
    __syncthreads();

    // ---------------- Phase B ----------------
    // Each wave: all 32 rows x 512 cols starting at wid*512. No barriers.
    const int wn2 = wid << 9;

    // hoist U fragments: uf[mf][ks] covers rows mf*16+fr, k = ks*32+fk..+8
    bf16x8 uf[2][4];
#pragma unroll
    for (int mf = 0; mf < 2; ++mf) {
        const int r = mf * 16 + fr;
#pragma unroll
        for (int ks = 0; ks < 4; ++ks)
            uf[mf][ks] = *reinterpret_cast<const bf16x8*>(
                &sU[r][(ks * 32 + fk) ^ ((r & 7) << 3)]);
    }

#pragma unroll 1
    for (int nc = 0; nc < 8; ++nc) {
        const int ncol = wn2 + nc * 64;
        // per-lane base into Bt for this chunk: row = ncol + fr, col = fk
        const __bf16* bbase = Bt + (size_t)(ncol + fr) * 128 + fk;

        f32x4 acc2[2][4] = {};
#pragma unroll
        for (int ks = 0; ks < 4; ++ks) {
#pragma unroll
            for (int nf = 0; nf < 4; ++nf) {
                bf16x8 bfv = *reinterpret_cast<const bf16x8*>(
                    bbase + (size_t)nf * 16 * 128 + ks * 32);
#pragma unroll
                for (int mf = 0; mf < 2; ++mf)
                    acc2[mf][nf] = __builtin_amdgcn_mfma_f32_16x16x32_bf16(
                        uf[mf][ks], bfv, acc2[mf][nf], 0, 0, 0);
            }
        }

        // store: 64B-contiguous segments per 16-lane group
#pragma unroll
        for (int mf = 0; mf < 2; ++mf) {
            const int orow = brow + mf * 16 + ((lane >> 4) << 2);
#pragma unroll
            for (int nf = 0; nf < 4; ++nf) {
                const int ocol = ncol + nf * 16 + fr;
#pragma unroll
                for (int v = 0; v < 4; ++v)
                    out[(size_t)(orow + v) * 4096 + ocol] = acc2[mf][nf][v];
            }
        }
    }
}

// ---------------------------------------------------------------------------
extern "C" void kernel_launch(void* const* d_in, const int* in_sizes, int n_in,
                              void* d_out, int out_size, void* d_ws, size_t ws_size,
                              hipStream_t stream) {
    const float* inp = (const float*)d_in[0];   // [8192,4096]
    const float* A   = (const float*)d_in[1];   // [4096,128]
    const float* B   = (const float*)d_in[2];   // [128,4096]
    float* out = (float*)d_out;                 // [8192,4096]

    char* ws = (char*)d_ws;
    __bf16* At = (__bf16*)(ws);                       // [128][4096]  1 MB
    __bf16* Bt = (__bf16*)(ws + (1 << 20));           // [4096][128]  1 MB

    // A[4096,128] -> At[128,4096];  B[128,4096] -> Bt[4096,128]
    tcast<<<dim3(128 / 32, 4096 / 32), 256, 0, stream>>>(A, At, 4096, 128);
    tcast<<<dim3(4096 / 32, 128 / 32), 256, 0, stream>>>(B, Bt, 128, 4096);

    fused_lora<<<256, 512, 0, stream>>>(inp, At, Bt, out);
}